// Round 1
// baseline (632.880 us; speedup 1.0000x reference)
//
#include <hip/hip_runtime.h>
#include <hip/hip_bf16.h>
#include <math.h>

// PaGCN forward, restructured:
//   h0 = relu(AM ⊙ spmm(adjZ, (M⊙x)@W0) + b0)      (spmm on 128 feats)
//   h1 = relu(AM ⊙ spmm(adjZ, (M⊙h0)@W1) + b1)     (spmm on 64 feats)
//   out = log_softmax(spmm(adj, h1@W2) + b2)        (spmm on 40 feats)
// Legal because spmm is linear in X and AM is a row scale (commutes with @W).
//
// CSR built per call (counting sort): histogram -> scan -> scatter producing
// row-sorted col/adj/adjZ arrays. SpMM is then wave-per-row, atomic-free.

__device__ __forceinline__ float rl_f(float v, int j) {
    return __builtin_bit_cast(float,
        __builtin_amdgcn_readlane(__builtin_bit_cast(int, v), j));
}
__device__ __forceinline__ int rl_i(int v, int j) {
    return __builtin_amdgcn_readlane(v, j);
}

// ---------------- CSR build ----------------

__global__ void hist_kernel(const int* __restrict__ row, int* __restrict__ cnt, int E) {
    int e = blockIdx.x * blockDim.x + threadIdx.x;
    if (e < E) atomicAdd(&cnt[row[e]], 1);
}

// each block scans 1024 elements (256 threads x 4)
__global__ void scan_part(const int* __restrict__ cnt, int* __restrict__ out,
                          int* __restrict__ bsums, int n) {
    __shared__ int sdata[256];
    const int t = threadIdx.x;
    const int base = blockIdx.x * 1024 + t * 4;
    int v[4];
#pragma unroll
    for (int i = 0; i < 4; ++i) v[i] = (base + i < n) ? cnt[base + i] : 0;
    int tsum = v[0] + v[1] + v[2] + v[3];
    sdata[t] = tsum;
    __syncthreads();
    for (int off = 1; off < 256; off <<= 1) {
        int x = (t >= off) ? sdata[t - off] : 0;
        __syncthreads();
        sdata[t] += x;
        __syncthreads();
    }
    int run = sdata[t] - tsum;  // exclusive within block
    if (t == 255) bsums[blockIdx.x] = sdata[t];
#pragma unroll
    for (int i = 0; i < 4; ++i) {
        if (base + i < n) out[base + i] = run;
        run += v[i];
    }
}

__global__ void scan_top(int* __restrict__ bs, int nb) {  // nb <= 64, 1 wave
    int t = threadIdx.x;
    int orig = (t < nb) ? bs[t] : 0;
    int v = orig;
#pragma unroll
    for (int off = 1; off < 64; off <<= 1) {
        int x = __shfl_up(v, off);
        if (t >= off) v += x;
    }
    if (t < nb) bs[t] = v - orig;  // exclusive
}

__global__ void scan_add(int* __restrict__ rp, const int* __restrict__ bs,
                         int* __restrict__ cursor, int n, int total) {
    int i = blockIdx.x * blockDim.x + threadIdx.x;
    if (i < n) {
        int v = rp[i] + bs[i >> 10];
        rp[i] = v;
        cursor[i] = v;
    }
    if (i == 0) rp[n] = total;
}

__global__ void scatter_kernel(const int* __restrict__ row, const int* __restrict__ col,
                               const float* __restrict__ vA, const float* __restrict__ vZ,
                               int* __restrict__ cursor, int* __restrict__ col_s,
                               float* __restrict__ vA_s, float* __restrict__ vZ_s, int E) {
    int e = blockIdx.x * blockDim.x + threadIdx.x;
    if (e >= E) return;
    int r = row[e];
    int pos = atomicAdd(&cursor[r], 1);
    col_s[pos] = col[e];
    vA_s[pos] = vA[e];
    vZ_s[pos] = vZ[e];
}

// ---------------- dense GEMM (fp32 vector ALU, readlane-broadcast A) ----------------
// Block: 256 threads = 4 waves; each wave computes 8 rows x COLS.
// W lives in LDS; A fragments in registers (lane = k index), broadcast via v_readlane.

template <int K, int COLS, bool MSCALE>
__launch_bounds__(256)
__global__ void gemm_rl(const float* __restrict__ A, const float* __restrict__ Mv,
                        const float* __restrict__ W, float* __restrict__ out, int n) {
    constexpr int KR = K / 64;                         // A regs per row
    constexpr int CR = (COLS % 64 == 0) ? COLS / 64 : 1;  // col regs per lane
    __shared__ float Ws[K * COLS];
    const int t = threadIdx.x;
    const int lane = t & 63;
    const int wid = t >> 6;

    for (int i = t * 4; i < K * COLS; i += 1024)
        *(float4*)&Ws[i] = *(const float4*)&W[i];
    __syncthreads();

    const int r0 = blockIdx.x * 32 + wid * 8;
    float af[8][KR];
#pragma unroll
    for (int i = 0; i < 8; ++i) {
        const int r = r0 + i;
        float m = 1.0f;
        if constexpr (MSCALE) { if (r < n) m = Mv[r]; }
#pragma unroll
        for (int j = 0; j < KR; ++j)
            af[i][j] = (r < n) ? A[(size_t)r * K + j * 64 + lane] * m : 0.0f;
    }

    float acc[8][CR];
#pragma unroll
    for (int i = 0; i < 8; ++i)
#pragma unroll
        for (int q = 0; q < CR; ++q) acc[i][q] = 0.0f;

#pragma unroll
    for (int k = 0; k < K; ++k) {
        float w[CR];
#pragma unroll
        for (int q = 0; q < CR; ++q) {
            if (COLS % 64 == 0) w[q] = Ws[k * COLS + q * 64 + lane];
            else w[q] = (lane < COLS) ? Ws[k * COLS + lane] : 0.0f;
        }
#pragma unroll
        for (int i = 0; i < 8; ++i) {
            const float a = rl_f(af[i][k >> 6], k & 63);
#pragma unroll
            for (int q = 0; q < CR; ++q) acc[i][q] += a * w[q];
        }
    }

#pragma unroll
    for (int i = 0; i < 8; ++i) {
        const int r = r0 + i;
        if (r >= n) continue;
        if (COLS % 64 == 0) {
#pragma unroll
            for (int q = 0; q < CR; ++q)
                out[(size_t)r * COLS + q * 64 + lane] = acc[i][q];
        } else if (lane < COLS) {
            out[(size_t)r * COLS + lane] = acc[i][0];
        }
    }
}

// ---------------- SpMM (wave per row, CSR, readlane edge broadcast) ----------------

template <int F, bool RELU, bool LSM>
__launch_bounds__(256)
__global__ void spmm_kernel(const float* __restrict__ vals, const int* __restrict__ cols,
                            const int* __restrict__ rp, const float* __restrict__ X,
                            const float* __restrict__ AM, const float* __restrict__ bias,
                            float* __restrict__ out, int n) {
    const int lane = threadIdx.x & 63;
    const int r = (int)((blockIdx.x * (unsigned)blockDim.x + threadIdx.x) >> 6);
    if (r >= n) return;
    // readfirstlane so the edge loop counter is provably scalar (v_readlane needs SGPR idx)
    const int s = __builtin_amdgcn_readfirstlane(rp[r]);
    const int e = __builtin_amdgcn_readfirstlane(rp[r + 1]);

    float acc0 = 0.0f, acc1 = 0.0f;
    for (int base = s; base < e; base += 64) {
        const int nn = min(64, e - base);
        float v = 0.0f; int c = 0;
        if (lane < nn) { v = vals[base + lane]; c = cols[base + lane]; }
        int j = 0;
        for (; j + 2 <= nn; j += 2) {
            const float v0 = rl_f(v, j);     const int c0 = rl_i(c, j);
            const float v1 = rl_f(v, j + 1); const int c1 = rl_i(c, j + 1);
            if (F == 128) {
                const float2 x0 = *(const float2*)(X + (size_t)c0 * F + lane * 2);
                const float2 x1 = *(const float2*)(X + (size_t)c1 * F + lane * 2);
                acc0 += v0 * x0.x; acc1 += v0 * x0.y;
                acc0 += v1 * x1.x; acc1 += v1 * x1.y;
            } else {
                const float x0 = (F == 64 || lane < F) ? X[(size_t)c0 * F + lane] : 0.0f;
                const float x1 = (F == 64 || lane < F) ? X[(size_t)c1 * F + lane] : 0.0f;
                acc0 += v0 * x0;
                acc0 += v1 * x1;
            }
        }
        if (j < nn) {
            const float v0 = rl_f(v, j); const int c0 = rl_i(c, j);
            if (F == 128) {
                const float2 x0 = *(const float2*)(X + (size_t)c0 * F + lane * 2);
                acc0 += v0 * x0.x; acc1 += v0 * x0.y;
            } else {
                const float x0 = (F == 64 || lane < F) ? X[(size_t)c0 * F + lane] : 0.0f;
                acc0 += v0 * x0;
            }
        }
    }

    if constexpr (LSM) {
        const float b = (lane < F) ? bias[lane] : 0.0f;
        const float vv = (lane < F) ? (acc0 + b) : -INFINITY;
        float mx = vv;
#pragma unroll
        for (int off = 32; off > 0; off >>= 1) mx = fmaxf(mx, __shfl_xor(mx, off));
        float sum = (lane < F) ? expf(vv - mx) : 0.0f;
#pragma unroll
        for (int off = 32; off > 0; off >>= 1) sum += __shfl_xor(sum, off);
        if (lane < F) out[(size_t)r * F + lane] = vv - mx - logf(sum);
    } else {
        const float am = AM[r];
        if (F == 128) {
            float o0 = acc0 * am + bias[2 * lane];
            float o1 = acc1 * am + bias[2 * lane + 1];
            if (RELU) { o0 = fmaxf(o0, 0.0f); o1 = fmaxf(o1, 0.0f); }
            *(float2*)(out + (size_t)r * F + lane * 2) = make_float2(o0, o1);
        } else {
            float o0 = acc0 * am + bias[lane];
            if (RELU) o0 = fmaxf(o0, 0.0f);
            out[(size_t)r * F + lane] = o0;
        }
    }
}

// ---------------- launch ----------------

extern "C" void kernel_launch(void* const* d_in, const int* in_sizes, int n_in,
                              void* d_out, int out_size, void* d_ws, size_t ws_size,
                              hipStream_t stream) {
    const float* x    = (const float*)d_in[0];
    const float* M    = (const float*)d_in[1];
    const float* AM   = (const float*)d_in[2];
    const float* adjv = (const float*)d_in[3];
    const float* adjZ = (const float*)d_in[4];
    const float* W0   = (const float*)d_in[5];
    const float* b0   = (const float*)d_in[6];
    const float* W1   = (const float*)d_in[7];
    const float* b1   = (const float*)d_in[8];
    const float* W2   = (const float*)d_in[9];
    const float* b2   = (const float*)d_in[10];
    const int* row    = (const int*)d_in[11];
    const int* col    = (const int*)d_in[12];
    float* out = (float*)d_out;

    const int n = in_sizes[1];   // N (M has N elements)
    const int E = in_sizes[3];   // edges

    // workspace layout (~61.3 MB)
    float* t_buf = (float*)d_ws;                 // N*128
    float* h_buf = t_buf + (size_t)n * 128;      // N*128
    int* cnt     = (int*)(h_buf + (size_t)n * 128);  // N
    int* rp      = cnt + n;                      // N+1
    int* bsums   = rp + (n + 1);                 // 64
    int* cursor  = bsums + 64;                   // N
    int* col_s   = cursor + n;                   // E
    float* vA_s  = (float*)(col_s + E);          // E
    float* vZ_s  = vA_s + E;                     // E

    // --- CSR build ---
    hipMemsetAsync(cnt, 0, (size_t)n * sizeof(int), stream);
    hist_kernel<<<(E + 255) / 256, 256, 0, stream>>>(row, cnt, E);
    const int nblk = (n + 1023) >> 10;  // 49 for N=50000 (<=64 required by scan_top)
    scan_part<<<nblk, 256, 0, stream>>>(cnt, rp, bsums, n);
    scan_top<<<1, 64, 0, stream>>>(bsums, nblk);
    scan_add<<<(n + 255) / 256, 256, 0, stream>>>(rp, bsums, cursor, n, E);
    scatter_kernel<<<(E + 255) / 256, 256, 0, stream>>>(row, col, adjv, adjZ, cursor,
                                                        col_s, vA_s, vZ_s, E);

    const int gemmBlocks = (n + 31) / 32;  // 32 rows per block
    const int spmmBlocks = (n + 3) / 4;    // 4 rows (waves) per block

    // layer 0: t0 = (M⊙x)@W0 ; h0 = relu(AM⊙spmm(adjZ,t0)+b0)
    gemm_rl<128, 128, true><<<gemmBlocks, 256, 0, stream>>>(x, M, W0, t_buf, n);
    spmm_kernel<128, true, false><<<spmmBlocks, 256, 0, stream>>>(vZ_s, col_s, rp, t_buf,
                                                                  AM, b0, h_buf, n);
    // layer 1: t1 = (M⊙h0)@W1 ; h1 = relu(AM⊙spmm(adjZ,t1)+b1)
    gemm_rl<128, 64, true><<<gemmBlocks, 256, 0, stream>>>(h_buf, M, W1, t_buf, n);
    spmm_kernel<64, true, false><<<spmmBlocks, 256, 0, stream>>>(vZ_s, col_s, rp, t_buf,
                                                                 AM, b1, h_buf, n);
    // layer 2: t2 = h1@W2 ; out = log_softmax(spmm(adj,t2)+b2)
    gemm_rl<64, 40, false><<<gemmBlocks, 256, 0, stream>>>(h_buf, nullptr, W2, t_buf, n);
    spmm_kernel<40, false, true><<<spmmBlocks, 256, 0, stream>>>(vA_s, col_s, rp, t_buf,
                                                                 AM, b2, out, n);
}

// Round 2
// 377.523 us; speedup vs baseline: 1.6764x; 1.6764x over previous
//
#include <hip/hip_runtime.h>
#include <hip/hip_bf16.h>
#include <math.h>

// PaGCN forward, restructured:
//   h0 = relu(AM ⊙ spmm(adjZ, (M⊙x)@W0) + b0)      (spmm on 128 feats)
//   h1 = relu(AM ⊙ spmm(adjZ, (M⊙h0)@W1) + b1)     (spmm on 64 feats)
//   out = log_softmax(spmm(adj, h1@W2) + b2)        (spmm on 40 feats)
// Legal because spmm is linear in X and AM is a row scale (commutes with @W).
//
// CSR built per call (counting sort): histogram -> scan -> scatter producing
// row-sorted col/adj/adjZ arrays. SpMM is then wave-per-row, atomic-free.
// GEMM: LDS-tiled fp32 (no fp32 MFMA on CDNA4), K-chunked, b128 LDS reads.

__device__ __forceinline__ float rl_f(float v, int j) {
    return __builtin_bit_cast(float,
        __builtin_amdgcn_readlane(__builtin_bit_cast(int, v), j));
}
__device__ __forceinline__ int rl_i(int v, int j) {
    return __builtin_amdgcn_readlane(v, j);
}

// ---------------- CSR build ----------------

__global__ void hist_kernel(const int* __restrict__ row, int* __restrict__ cnt, int E) {
    int e = blockIdx.x * blockDim.x + threadIdx.x;
    if (e < E) atomicAdd(&cnt[row[e]], 1);
}

// each block scans 1024 elements (256 threads x 4)
__global__ void scan_part(const int* __restrict__ cnt, int* __restrict__ out,
                          int* __restrict__ bsums, int n) {
    __shared__ int sdata[256];
    const int t = threadIdx.x;
    const int base = blockIdx.x * 1024 + t * 4;
    int v[4];
#pragma unroll
    for (int i = 0; i < 4; ++i) v[i] = (base + i < n) ? cnt[base + i] : 0;
    int tsum = v[0] + v[1] + v[2] + v[3];
    sdata[t] = tsum;
    __syncthreads();
    for (int off = 1; off < 256; off <<= 1) {
        int x = (t >= off) ? sdata[t - off] : 0;
        __syncthreads();
        sdata[t] += x;
        __syncthreads();
    }
    int run = sdata[t] - tsum;  // exclusive within block
    if (t == 255) bsums[blockIdx.x] = sdata[t];
#pragma unroll
    for (int i = 0; i < 4; ++i) {
        if (base + i < n) out[base + i] = run;
        run += v[i];
    }
}

__global__ void scan_top(int* __restrict__ bs, int nb) {  // nb <= 64, 1 wave
    int t = threadIdx.x;
    int orig = (t < nb) ? bs[t] : 0;
    int v = orig;
#pragma unroll
    for (int off = 1; off < 64; off <<= 1) {
        int x = __shfl_up(v, off);
        if (t >= off) v += x;
    }
    if (t < nb) bs[t] = v - orig;  // exclusive
}

__global__ void scan_add(int* __restrict__ rp, const int* __restrict__ bs,
                         int* __restrict__ cursor, int n, int total) {
    int i = blockIdx.x * blockDim.x + threadIdx.x;
    if (i < n) {
        int v = rp[i] + bs[i >> 10];
        rp[i] = v;
        cursor[i] = v;
    }
    if (i == 0) rp[n] = total;
}

__global__ void scatter_kernel(const int* __restrict__ row, const int* __restrict__ col,
                               const float* __restrict__ vA, const float* __restrict__ vZ,
                               int* __restrict__ cursor, int* __restrict__ col_s,
                               float* __restrict__ vA_s, float* __restrict__ vZ_s, int E) {
    int e = blockIdx.x * blockDim.x + threadIdx.x;
    if (e >= E) return;
    int r = row[e];
    int pos = atomicAdd(&cursor[r], 1);
    col_s[pos] = col[e];
    vA_s[pos] = vA[e];
    vZ_s[pos] = vZ[e];
}

// ---------------- dense GEMM (fp32, LDS-tiled) ----------------
// 256 threads/block. Thread owns RPT=8 rows (strided by RG) x CPT cols.
// K-chunks of 32 staged in LDS: As[ROWS][32+4pad] (pad=4 keeps b128 alignment
// AND makes consecutive rows start 4 banks apart -> conflict-free for 2/4/8
// row-groups per wave), Ws[32][COLS].

template <int K, int COLS, int CPT, bool MSCALE>
__launch_bounds__(256)
__global__ void gemm_tile(const float* __restrict__ A, const float* __restrict__ Mv,
                          const float* __restrict__ W, float* __restrict__ out, int n) {
    constexpr int TC = COLS / CPT;     // threads spanning the col dim
    constexpr int RG = 256 / TC;       // row-groups (distinct rows in flight)
    constexpr int RPT = 8;
    constexpr int ROWS = RG * RPT;
    constexpr int KT = 32;
    constexpr int AP = KT + 4;         // padded lead dim (floats)
    static_assert(COLS % CPT == 0 && 256 % TC == 0, "bad tiling");

    __shared__ float As[ROWS * AP];
    __shared__ float Ws[KT * COLS];

    const int t = threadIdx.x;
    const int rg = t / TC;             // this thread's row-group
    const int c0 = (t % TC) * CPT;
    const int r0 = blockIdx.x * ROWS;

    float acc[RPT][CPT];
#pragma unroll
    for (int i = 0; i < RPT; ++i)
#pragma unroll
        for (int c = 0; c < CPT; ++c) acc[i][c] = 0.0f;

    for (int k0 = 0; k0 < K; k0 += KT) {
        __syncthreads();
        // stage A chunk (ROWS x 32) as float4, with optional M row-scale
        for (int e = t; e < ROWS * (KT / 4); e += 256) {
            const int row = e / (KT / 4);
            const int kq = e % (KT / 4);
            const int r = r0 + row;
            float4 v = make_float4(0.f, 0.f, 0.f, 0.f);
            if (r < n) {
                v = *(const float4*)&A[(size_t)r * K + k0 + kq * 4];
                if constexpr (MSCALE) {
                    const float m = Mv[r];
                    v.x *= m; v.y *= m; v.z *= m; v.w *= m;
                }
            }
            *(float4*)&As[row * AP + kq * 4] = v;
        }
        // stage W chunk (32 x COLS) — contiguous copy
        for (int i = t * 4; i < KT * COLS; i += 1024)
            *(float4*)&Ws[i] = *(const float4*)&W[(size_t)k0 * COLS + i];
        __syncthreads();

#pragma unroll
        for (int kk = 0; kk < KT; kk += 4) {
            float w[4][CPT];
#pragma unroll
            for (int kj = 0; kj < 4; ++kj)
#pragma unroll
                for (int c = 0; c < CPT; ++c)
                    w[kj][c] = Ws[(kk + kj) * COLS + c0 + c];
#pragma unroll
            for (int i = 0; i < RPT; ++i) {
                const float4 av = *(const float4*)&As[(rg + i * RG) * AP + kk];
#pragma unroll
                for (int c = 0; c < CPT; ++c) {
                    acc[i][c] += av.x * w[0][c];
                    acc[i][c] += av.y * w[1][c];
                    acc[i][c] += av.z * w[2][c];
                    acc[i][c] += av.w * w[3][c];
                }
            }
        }
    }

#pragma unroll
    for (int i = 0; i < RPT; ++i) {
        const int r = r0 + rg + i * RG;
        if (r >= n) continue;
#pragma unroll
        for (int c = 0; c < CPT; ++c)
            out[(size_t)r * COLS + c0 + c] = acc[i][c];
    }
}

// ---------------- SpMM (wave per row, CSR, readlane edge broadcast) ----------------

template <int F, bool RELU, bool LSM>
__launch_bounds__(256)
__global__ void spmm_kernel(const float* __restrict__ vals, const int* __restrict__ cols,
                            const int* __restrict__ rp, const float* __restrict__ X,
                            const float* __restrict__ AM, const float* __restrict__ bias,
                            float* __restrict__ out, int n) {
    const int lane = threadIdx.x & 63;
    const int r = (int)((blockIdx.x * (unsigned)blockDim.x + threadIdx.x) >> 6);
    if (r >= n) return;
    // readfirstlane so the edge loop counter is provably scalar (v_readlane needs SGPR idx)
    const int s = __builtin_amdgcn_readfirstlane(rp[r]);
    const int e = __builtin_amdgcn_readfirstlane(rp[r + 1]);

    float acc0 = 0.0f, acc1 = 0.0f;
    for (int base = s; base < e; base += 64) {
        const int nn = min(64, e - base);
        float v = 0.0f; int c = 0;
        if (lane < nn) { v = vals[base + lane]; c = cols[base + lane]; }
        int j = 0;
        for (; j + 2 <= nn; j += 2) {
            const float v0 = rl_f(v, j);     const int c0 = rl_i(c, j);
            const float v1 = rl_f(v, j + 1); const int c1 = rl_i(c, j + 1);
            if (F == 128) {
                const float2 x0 = *(const float2*)(X + (size_t)c0 * F + lane * 2);
                const float2 x1 = *(const float2*)(X + (size_t)c1 * F + lane * 2);
                acc0 += v0 * x0.x; acc1 += v0 * x0.y;
                acc0 += v1 * x1.x; acc1 += v1 * x1.y;
            } else {
                const float x0 = (F == 64 || lane < F) ? X[(size_t)c0 * F + lane] : 0.0f;
                const float x1 = (F == 64 || lane < F) ? X[(size_t)c1 * F + lane] : 0.0f;
                acc0 += v0 * x0;
                acc0 += v1 * x1;
            }
        }
        if (j < nn) {
            const float v0 = rl_f(v, j); const int c0 = rl_i(c, j);
            if (F == 128) {
                const float2 x0 = *(const float2*)(X + (size_t)c0 * F + lane * 2);
                acc0 += v0 * x0.x; acc1 += v0 * x0.y;
            } else {
                const float x0 = (F == 64 || lane < F) ? X[(size_t)c0 * F + lane] : 0.0f;
                acc0 += v0 * x0;
            }
        }
    }

    if constexpr (LSM) {
        const float b = (lane < F) ? bias[lane] : 0.0f;
        const float vv = (lane < F) ? (acc0 + b) : -INFINITY;
        float mx = vv;
#pragma unroll
        for (int off = 32; off > 0; off >>= 1) mx = fmaxf(mx, __shfl_xor(mx, off));
        float sum = (lane < F) ? expf(vv - mx) : 0.0f;
#pragma unroll
        for (int off = 32; off > 0; off >>= 1) sum += __shfl_xor(sum, off);
        if (lane < F) out[(size_t)r * F + lane] = vv - mx - logf(sum);
    } else {
        const float am = AM[r];
        if (F == 128) {
            float o0 = acc0 * am + bias[2 * lane];
            float o1 = acc1 * am + bias[2 * lane + 1];
            if (RELU) { o0 = fmaxf(o0, 0.0f); o1 = fmaxf(o1, 0.0f); }
            *(float2*)(out + (size_t)r * F + lane * 2) = make_float2(o0, o1);
        } else {
            float o0 = acc0 * am + bias[lane];
            if (RELU) o0 = fmaxf(o0, 0.0f);
            out[(size_t)r * F + lane] = o0;
        }
    }
}

// ---------------- launch ----------------

extern "C" void kernel_launch(void* const* d_in, const int* in_sizes, int n_in,
                              void* d_out, int out_size, void* d_ws, size_t ws_size,
                              hipStream_t stream) {
    const float* x    = (const float*)d_in[0];
    const float* M    = (const float*)d_in[1];
    const float* AM   = (const float*)d_in[2];
    const float* adjv = (const float*)d_in[3];
    const float* adjZ = (const float*)d_in[4];
    const float* W0   = (const float*)d_in[5];
    const float* b0   = (const float*)d_in[6];
    const float* W1   = (const float*)d_in[7];
    const float* b1   = (const float*)d_in[8];
    const float* W2   = (const float*)d_in[9];
    const float* b2   = (const float*)d_in[10];
    const int* row    = (const int*)d_in[11];
    const int* col    = (const int*)d_in[12];
    float* out = (float*)d_out;

    const int n = in_sizes[1];   // N (M has N elements)
    const int E = in_sizes[3];   // edges

    // workspace layout (~61.3 MB)
    float* t_buf = (float*)d_ws;                 // N*128
    float* h_buf = t_buf + (size_t)n * 128;      // N*128
    int* cnt     = (int*)(h_buf + (size_t)n * 128);  // N
    int* rp      = cnt + n;                      // N+1
    int* bsums   = rp + (n + 1);                 // 64
    int* cursor  = bsums + 64;                   // N
    int* col_s   = cursor + n;                   // E
    float* vA_s  = (float*)(col_s + E);          // E
    float* vZ_s  = vA_s + E;                     // E

    // --- CSR build ---
    hipMemsetAsync(cnt, 0, (size_t)n * sizeof(int), stream);
    hist_kernel<<<(E + 255) / 256, 256, 0, stream>>>(row, cnt, E);
    const int nblk = (n + 1023) >> 10;  // 49 for N=50000 (<=64 required by scan_top)
    scan_part<<<nblk, 256, 0, stream>>>(cnt, rp, bsums, n);
    scan_top<<<1, 64, 0, stream>>>(bsums, nblk);
    scan_add<<<(n + 255) / 256, 256, 0, stream>>>(rp, bsums, cursor, n, E);
    scatter_kernel<<<(E + 255) / 256, 256, 0, stream>>>(row, col, adjv, adjZ, cursor,
                                                        col_s, vA_s, vZ_s, E);

    const int spmmBlocks = (n + 3) / 4;    // 4 rows (waves) per block

    // layer 0: t0 = (M⊙x)@W0 ; h0 = relu(AM⊙spmm(adjZ,t0)+b0)
    gemm_tile<128, 128, 4, true><<<(n + 63) / 64, 256, 0, stream>>>(x, M, W0, t_buf, n);
    spmm_kernel<128, true, false><<<spmmBlocks, 256, 0, stream>>>(vZ_s, col_s, rp, t_buf,
                                                                  AM, b0, h_buf, n);
    // layer 1: t1 = (M⊙h0)@W1 ; h1 = relu(AM⊙spmm(adjZ,t1)+b1)
    gemm_tile<128, 64, 4, true><<<(n + 127) / 128, 256, 0, stream>>>(h_buf, M, W1, t_buf, n);
    spmm_kernel<64, true, false><<<spmmBlocks, 256, 0, stream>>>(vZ_s, col_s, rp, t_buf,
                                                                 AM, b1, h_buf, n);
    // layer 2: t2 = h1@W2 ; out = log_softmax(spmm(adj,t2)+b2)
    gemm_tile<64, 40, 5, false><<<(n + 255) / 256, 256, 0, stream>>>(h_buf, nullptr, W2, t_buf, n);
    spmm_kernel<40, false, true><<<spmmBlocks, 256, 0, stream>>>(vA_s, col_s, rp, t_buf,
                                                                 AM, b2, out, n);
}